// Round 11
// baseline (953.912 us; speedup 1.0000x reference)
//
#include <hip/hip_runtime.h>
#include <hip/hip_bf16.h>

#define NN 10000
#define EE 160000
#define LL 6

#define INV_SQRT_3f  0.57735026919f
#define INV_SQRT_Hf  0.08838834764832f
#define INV_SQRT_2f  0.70710678118655f

typedef _Float16 half8 __attribute__((ext_vector_type(8)));
typedef float f32x4 __attribute__((ext_vector_type(4)));

#define WE1OFF   0
#define WV1OFF   8192
#define WV2OFF   24576
#define WU1OFF   32768
#define WU2OFF   65536
#define G2V1OFF  81920
#define G2U1OFF  86016
#define WFIN_SZ  94208

__device__ __forceinline__ float ssilu_f(float v){
  float s = 1.0f / (1.0f + __expf(-v));
  return v * s * 1.6666666666667f;
}

// ---------------- CSR build ----------------
__global__ __launch_bounds__(256) void k_hist(const int* __restrict__ edst, int* __restrict__ cnt){
  int i = blockIdx.x*256 + threadIdx.x;
  if (i < EE) atomicAdd(&cnt[edst[i]], 1);
}

__global__ __launch_bounds__(1024) void k_scan(const int* __restrict__ cnt,
                                               int* __restrict__ off, int* __restrict__ cur){
  __shared__ int ps[1024];
  int t = threadIdx.x;
  int base = t*10;
  int local[10];
  int s = 0;
  #pragma unroll
  for (int i=0;i<10;i++){
    int c = (base+i < NN) ? cnt[base+i] : 0;
    local[i] = s; s += c;
  }
  ps[t] = s;
  __syncthreads();
  for (int d=1; d<1024; d<<=1){
    int v = (t>=d) ? ps[t-d] : 0;
    __syncthreads();
    ps[t] += v;
    __syncthreads();
  }
  int pre = (t>0) ? ps[t-1] : 0;
  #pragma unroll
  for (int i=0;i<10;i++){
    int idx = base+i;
    if (idx < NN){ int o = pre + local[i]; off[idx]=o; cur[idx]=o; }
  }
  if (t==1023) off[NN] = ps[1023];
}

__global__ __launch_bounds__(256) void k_fill(const int* __restrict__ edst,
                                              int* __restrict__ cur, int* __restrict__ eord){
  int i = blockIdx.x*256 + threadIdx.x;
  if (i < EE){
    int d = edst[i];
    int p = atomicAdd(&cur[d], 1);
    eord[p] = i;
  }
}

// ---------------- edge pre-sort (once; eord is layer-invariant) ----------------
__global__ __launch_bounds__(256) void k_sorta(const float* __restrict__ erbf,
                                               const int* __restrict__ eord, _Float16* __restrict__ eA){
  long i = (long)blockIdx.x*256 + threadIdx.x;
  if (i >= (long)EE*64) return;
  int j = i & 7, lane = (i >> 3) & 63, kh = (i >> 9) & 1;
  long tile = i >> 10;
  int e = eord[tile*16 + (lane&15)];
  eA[i] = (_Float16)erbf[(size_t)e*64 + kh*32 + (lane>>4)*8 + j];
}

__global__ __launch_bounds__(256) void k_sorte(const int* __restrict__ esrc, const float* __restrict__ evec,
                                               const int* __restrict__ eord, float4* __restrict__ es4){
  int p = blockIdx.x*256 + threadIdx.x;
  if (p >= EE) return;
  int e = eord[p];
  es4[p] = make_float4(evec[(size_t)e*3], evec[(size_t)e*3+1], evec[(size_t)e*3+2],
                       __int_as_float(esrc[e]));
}

// ---------------- pack rbf_w into f16 MFMA B-fragment layout (+ INV_SQRT_3 fold) ----------------
__global__ __launch_bounds__(256) void k_packw(const float* __restrict__ w, _Float16* __restrict__ wf){
  int i = blockIdx.x*256 + threadIdx.x;
  if (i >= LL*24*2*64*8) return;
  int j    = i & 7;
  int lane = (i >> 3) & 63;
  int kh   = (i >> 9) & 1;
  int rest = i >> 10;          // l*24 + nb
  int nb   = rest % 24;
  int l    = rest / 24;
  int k    = 32*kh + 8*(lane>>4) + j;
  int ch   = nb*16 + (lane&15);
  float v = w[((size_t)l*64 + k)*384 + ch];
  if (ch >= 128 && ch < 256) v *= INV_SQRT_3f;
  wf[i] = (_Float16)v;
}

__global__ __launch_bounds__(256) void k_packb(const float* __restrict__ b, float* __restrict__ bsc){
  int i = blockIdx.x*256 + threadIdx.x;
  if (i >= LL*384) return;
  int ch = i % 384;
  float v = b[i];
  if (ch >= 128 && ch < 256) v *= INV_SQRT_3f;
  bsc[i] = v;
}

// ---------------- generic pack: f32 [K][NO] -> f16 B-fragment order ----------------
struct PackTab {
  const float* s[40];
  _Float16* d[40];
  int K[40];
  int NO[40];
};
__global__ __launch_bounds__(256) void k_packall(PackTab tb){
  int e = blockIdx.y;
  int K = tb.K[e], NO = tb.NO[e];
  int tot = K*NO, KS = K >> 5;
  const float* s = tb.s[e];
  _Float16* d = tb.d[e];
  for (int i = blockIdx.x*256 + threadIdx.x; i < tot; i += gridDim.x*256){
    int j = i & 7, lane = (i >> 3) & 63, rest = i >> 9;
    int ks = rest % KS, nb = rest / KS;
    int k = ks*32 + (lane>>4)*8 + j, n = nb*16 + (lane&15);
    d[i] = (_Float16)s[(size_t)k*NO + n];
  }
}

// init vec half of xv16
__global__ __launch_bounds__(256) void k_cvt16v(const float* __restrict__ v, _Float16* __restrict__ xv){
  int i = blockIdx.x*256 + threadIdx.x;
  if (i >= NN*384) return;
  int node = i / 384, r = i % 384;
  xv[(size_t)node*768 + 384 + r] = (_Float16)v[i];
}

// ---------------- merged per-layer kernel A: xh MLP (blocks 0..312) + rbfh GEMM (blocks 313..937) ----------------
__global__ __launch_bounds__(256) void k_xhgemm(
    const float* __restrict__ x,
    const float* __restrict__ lnw, const float* __restrict__ lnb,
    const _Float16* __restrict__ wf1, const float* __restrict__ b1,
    const _Float16* __restrict__ wf2, const float* __restrict__ b2,
    _Float16* __restrict__ xv16,
    const _Float16* __restrict__ eA, const _Float16* __restrict__ wf,
    const float* __restrict__ bsc, _Float16* __restrict__ rbfh)
{
  __shared__ _Float16 sA[32][136];
  __shared__ _Float16 sH[32][136];
  int t = threadIdx.x;
  if (blockIdx.x >= 313){
    int ob = (blockIdx.x - 313)*4 + (t >> 6);   // 0..2499
    int lane = t & 63;
    int i0 = ob * 64;
    int tg = ob * 4;
    int ml = lane & 15, kg = lane >> 4;
    half8 a0[4], a1[4];
    #pragma unroll
    for (int tt = 0; tt < 4; tt++){
      a0[tt] = *(const half8*)(eA + ((size_t)((tg+tt)*2+0)*64 + lane)*8);
      a1[tt] = *(const half8*)(eA + ((size_t)((tg+tt)*2+1)*64 + lane)*8);
    }
    #pragma unroll 2
    for (int nb = 0; nb < 24; nb++){
      half8 b0 = *(const half8*)(wf + ((size_t)(nb*2+0)*64 + lane)*8);
      half8 b1h = *(const half8*)(wf + ((size_t)(nb*2+1)*64 + lane)*8);
      float bias = bsc[nb*16 + ml];
      #pragma unroll
      for (int tt = 0; tt < 4; tt++){
        f32x4 acc = {bias, bias, bias, bias};
        acc = __builtin_amdgcn_mfma_f32_16x16x32_f16(a0[tt], b0, acc, 0, 0, 0);
        acc = __builtin_amdgcn_mfma_f32_16x16x32_f16(a1[tt], b1h, acc, 0, 0, 0);
        _Float16* orow = rbfh + (size_t)(i0 + tt*16)*384 + nb*16 + ml;
        #pragma unroll
        for (int r = 0; r < 4; r++)
          orow[(size_t)(kg*4 + r)*384] = (_Float16)acc[r];
      }
    }
    return;
  }
  int n0 = blockIdx.x * 32;
  {
    int nd = t >> 3, sb = t & 7;
    int node = n0 + nd;
    float v[16];
    float s = 0.f, ss = 0.f;
    if (node < NN){
      const float* xr = x + (size_t)node*128 + sb*16;
      #pragma unroll
      for (int g = 0; g < 4; g++){
        float4 q = *(const float4*)(xr + g*4);
        v[g*4+0]=q.x; v[g*4+1]=q.y; v[g*4+2]=q.z; v[g*4+3]=q.w;
      }
      #pragma unroll
      for (int u = 0; u < 16; u++){ s += v[u]; ss += v[u]*v[u]; }
    } else {
      #pragma unroll
      for (int u = 0; u < 16; u++) v[u] = 0.f;
    }
    #pragma unroll
    for (int o2 = 4; o2 > 0; o2 >>= 1){
      s  += __shfl_xor(s, o2, 8);
      ss += __shfl_xor(ss, o2, 8);
    }
    float mean = s * (1.0f/128.0f);
    float var  = ss * (1.0f/128.0f) - mean*mean;
    float rstd = rsqrtf(var + 1e-5f);
    #pragma unroll
    for (int u = 0; u < 16; u++){
      int h = sb*16 + u;
      sA[nd][h] = (node < NN) ? (_Float16)((v[u]-mean)*rstd*lnw[h] + lnb[h]) : (_Float16)0.f;
    }
  }
  __syncthreads();
  int lane = t & 63, w = t >> 6, ml = lane & 15, kg = lane >> 4;
  int mt = w >> 1;
  {
    half8 a[4];
    #pragma unroll
    for (int ks = 0; ks < 4; ks++)
      a[ks] = *(const half8*)&sA[mt*16 + ml][ks*32 + kg*8];
    float hout[4][4];
    #pragma unroll
    for (int nb4 = 0; nb4 < 4; nb4++){
      int nb = (w&1)*4 + nb4;
      float bias = b1[nb*16 + ml];
      f32x4 acc = {bias, bias, bias, bias};
      #pragma unroll
      for (int ks = 0; ks < 4; ks++)
        acc = __builtin_amdgcn_mfma_f32_16x16x32_f16(a[ks],
                *(const half8*)(wf1 + ((size_t)(nb*4+ks)*64 + lane)*8), acc, 0,0,0);
      #pragma unroll
      for (int r = 0; r < 4; r++) hout[nb4][r] = ssilu_f(acc[r]);
    }
    #pragma unroll
    for (int nb4 = 0; nb4 < 4; nb4++){
      int nb = (w&1)*4 + nb4;
      #pragma unroll
      for (int r = 0; r < 4; r++)
        sH[mt*16 + kg*4 + r][nb*16 + ml] = (_Float16)hout[nb4][r];
    }
  }
  __syncthreads();
  {
    half8 a[4];
    #pragma unroll
    for (int ks = 0; ks < 4; ks++)
      a[ks] = *(const half8*)&sH[mt*16 + ml][ks*32 + kg*8];
    #pragma unroll 4
    for (int nb12 = 0; nb12 < 12; nb12++){
      int nb = (w&1)*12 + nb12;
      float bias = b2[nb*16 + ml];
      f32x4 acc = {bias, bias, bias, bias};
      #pragma unroll
      for (int ks = 0; ks < 4; ks++)
        acc = __builtin_amdgcn_mfma_f32_16x16x32_f16(a[ks],
                *(const half8*)(wf2 + ((size_t)(nb*4+ks)*64 + lane)*8), acc, 0,0,0);
      #pragma unroll
      for (int r = 0; r < 4; r++){
        int m = mt*16 + kg*4 + r;
        int node = n0 + m;
        if (node < NN) xv16[(size_t)node*768 + nb*16 + ml] = (_Float16)acc[r];
      }
    }
  }
}

// ---------------- edge kernel: one wave per dst node, prefetched es4, interleaved xv16 gathers ----------------
__global__ __launch_bounds__(256) void k_edge3(
    const _Float16* __restrict__ rbfh,
    const float4* __restrict__ es4, const int* __restrict__ off,
    const _Float16* __restrict__ xv16,
    _Float16* __restrict__ dx, _Float16* __restrict__ dvec)
{
  int t = threadIdx.x;
  int lane = t & 63;
  int n = blockIdx.x*4 + (t>>6);
  if (n >= NN) return;
  int o0 = off[n], o1 = off[n+1];
  float ax0 = 0.f, ax1 = 0.f;
  float av00=0.f, av01=0.f, av10=0.f, av11=0.f, av20=0.f, av21=0.f;
  float4 q = (o0 < o1) ? es4[o0] : make_float4(0.f,0.f,0.f,0.f);
  #pragma unroll 2
  for (int p = o0; p < o1; p++){
    float4 qn = (p+1 < o1) ? es4[p+1] : q;
    const _Float16* hr = rbfh + (size_t)p*384;
    float h0 = (float)hr[lane];
    float h1 = (float)hr[64+lane];
    float h2 = (float)hr[128+lane];
    float h3 = (float)hr[192+lane];
    float h4 = (float)hr[256+lane];
    float h5 = (float)hr[320+lane];
    int sN = __float_as_int(q.w);
    const _Float16* xr = xv16 + (size_t)sN*768;
    float m0  = h0 * (float)xr[lane];
    float m1  = h1 * (float)xr[64+lane];
    float m2a = h2 * (float)xr[128+lane];
    float m2b = h3 * (float)xr[192+lane];
    float m3a = h4 * (float)xr[256+lane];
    float m3b = h5 * (float)xr[320+lane];
    ax0 += m0; ax1 += m1;
    const _Float16* vr = xr + 384;
    av00 = fmaf((float)vr[lane],     m2a, av00); av00 = fmaf(m3a, q.x, av00);
    av01 = fmaf((float)vr[64+lane],  m2b, av01); av01 = fmaf(m3b, q.x, av01);
    av10 = fmaf((float)vr[128+lane], m2a, av10); av10 = fmaf(m3a, q.y, av10);
    av11 = fmaf((float)vr[192+lane], m2b, av11); av11 = fmaf(m3b, q.y, av11);
    av20 = fmaf((float)vr[256+lane], m2a, av20); av20 = fmaf(m3a, q.z, av20);
    av21 = fmaf((float)vr[320+lane], m2b, av21); av21 = fmaf(m3b, q.z, av21);
    q = qn;
  }
  _Float16* dxr = dx + (size_t)n*128;
  dxr[lane] = (_Float16)ax0; dxr[64+lane] = (_Float16)ax1;
  _Float16* dvr = dvec + (size_t)n*384;
  dvr[lane]     = (_Float16)(av00 * INV_SQRT_Hf);
  dvr[64+lane]  = (_Float16)(av01 * INV_SQRT_Hf);
  dvr[128+lane] = (_Float16)(av10 * INV_SQRT_Hf);
  dvr[192+lane] = (_Float16)(av11 * INV_SQRT_Hf);
  dvr[256+lane] = (_Float16)(av20 * INV_SQRT_Hf);
  dvr[320+lane] = (_Float16)(av21 * INV_SQRT_Hf);
}

// ---------------- node update (MFMA, 32 nodes/block), vec master = f16 xv16 ----------------
__global__ __launch_bounds__(256) void k_node_mfma(
    float* __restrict__ xbuf,
    const _Float16* __restrict__ dx, const _Float16* __restrict__ dvec,
    const _Float16* __restrict__ wfvp,
    const _Float16* __restrict__ wfxv1, const float* __restrict__ xv1_b,
    const _Float16* __restrict__ wfxv2, const float* __restrict__ xv2_b,
    _Float16* __restrict__ xv16)
{
  __shared__ _Float16 sCat[32][264];
  int t = threadIdx.x;
  int n0 = blockIdx.x * 32;
  int lane = t & 63, w = t >> 6, ml = lane & 15, kg = lane >> 4;
  int mt = w & 1, nbb = (w >> 1) * 4;
  float v1g[3][4][4];
  float vdg[4][4];
  float vn[4][4];
  #pragma unroll
  for (int i=0;i<4;i++){
    #pragma unroll
    for (int r=0;r<4;r++){ vdg[i][r]=0.f; vn[i][r]=0.f; }
  }
  int arow = n0 + mt*16 + ml;
  bool aok = arow < NN;
  #pragma unroll
  for (int cd = 0; cd < 3; cd++){
    half8 a[4];
    #pragma unroll
    for (int ks = 0; ks < 4; ks++){
      if (aok){
        const _Float16* vr16 = xv16 + (size_t)arow*768 + 384 + cd*128 + ks*32 + kg*8;
        const _Float16* dr = dvec + (size_t)arow*384 + cd*128 + ks*32 + kg*8;
        half8 vh = *(const half8*)(vr16);
        half8 dh = *(const half8*)(dr);
        #pragma unroll
        for (int j = 0; j < 8; j++)
          a[ks][j] = (_Float16)((float)vh[j] + (float)dh[j]);
      } else {
        #pragma unroll
        for (int j=0;j<8;j++) a[ks][j] = (_Float16)0.f;
      }
    }
    #pragma unroll
    for (int nb4 = 0; nb4 < 4; nb4++){
      int nb1 = nbb + nb4;
      f32x4 acc1 = {0.f,0.f,0.f,0.f}, acc2 = {0.f,0.f,0.f,0.f};
      #pragma unroll
      for (int ks = 0; ks < 4; ks++){
        acc1 = __builtin_amdgcn_mfma_f32_16x16x32_f16(a[ks],
                 *(const half8*)(wfvp + ((size_t)(nb1*4+ks)*64 + lane)*8), acc1, 0,0,0);
        acc2 = __builtin_amdgcn_mfma_f32_16x16x32_f16(a[ks],
                 *(const half8*)(wfvp + ((size_t)((nb1+8)*4+ks)*64 + lane)*8), acc2, 0,0,0);
      }
      #pragma unroll
      for (int r = 0; r < 4; r++){
        float v1v = acc1[r], v2v = acc2[r];
        vdg[nb4][r] += v1v*v2v;
        vn[nb4][r] += v2v*v2v;
        v1g[cd][nb4][r] = v1v;
      }
    }
  }
  #pragma unroll
  for (int nb4 = 0; nb4 < 4; nb4++){
    #pragma unroll
    for (int r = 0; r < 4; r++){
      int m = mt*16 + kg*4 + r, c = (nbb+nb4)*16 + ml;
      vdg[nb4][r] *= INV_SQRT_Hf;
      sCat[m][128 + c] = (_Float16)sqrtf(vn[nb4][r] + 1e-8f);
    }
  }
  {
    int nd = t >> 3, sb = t & 7;
    int node = n0 + nd;
    if (node < NN){
      const float* xr = xbuf + (size_t)node*128 + sb*16;
      const _Float16* dr = dx + (size_t)node*128 + sb*16;
      half8 da = *(const half8*)(dr);
      half8 db = *(const half8*)(dr+8);
      #pragma unroll
      for (int g = 0; g < 4; g++){
        float4 qa = *(const float4*)(xr + g*4);
        float d0 = (float)((g<2)?da[g*4+0]:db[(g-2)*4+0]);
        float d1 = (float)((g<2)?da[g*4+1]:db[(g-2)*4+1]);
        float d2 = (float)((g<2)?da[g*4+2]:db[(g-2)*4+2]);
        float d3 = (float)((g<2)?da[g*4+3]:db[(g-2)*4+3]);
        sCat[nd][sb*16+g*4+0] = (_Float16)((qa.x+d0)*INV_SQRT_2f);
        sCat[nd][sb*16+g*4+1] = (_Float16)((qa.y+d1)*INV_SQRT_2f);
        sCat[nd][sb*16+g*4+2] = (_Float16)((qa.z+d2)*INV_SQRT_2f);
        sCat[nd][sb*16+g*4+3] = (_Float16)((qa.w+d3)*INV_SQRT_2f);
      }
    } else {
      #pragma unroll
      for (int u = 0; u < 16; u++) sCat[nd][sb*16+u] = (_Float16)0.f;
    }
  }
  __syncthreads();
  float hreg[4][4];
  {
    half8 a[8];
    #pragma unroll
    for (int ks = 0; ks < 8; ks++)
      a[ks] = *(const half8*)&sCat[mt*16 + ml][ks*32 + kg*8];
    #pragma unroll
    for (int nb4 = 0; nb4 < 4; nb4++){
      int nb = (w>>1)*4 + nb4;
      float bias = xv1_b[nb*16 + ml];
      f32x4 acc = {bias, bias, bias, bias};
      #pragma unroll
      for (int ks = 0; ks < 8; ks++)
        acc = __builtin_amdgcn_mfma_f32_16x16x32_f16(a[ks],
                *(const half8*)(wfxv1 + ((size_t)(nb*8+ks)*64 + lane)*8), acc, 0,0,0);
      #pragma unroll
      for (int r = 0; r < 4; r++) hreg[nb4][r] = ssilu_f(acc[r]);
    }
  }
  __syncthreads();
  #pragma unroll
  for (int nb4 = 0; nb4 < 4; nb4++){
    int nb = (w>>1)*4 + nb4;
    #pragma unroll
    for (int r = 0; r < 4; r++)
      sCat[mt*16 + kg*4 + r][nb*16 + ml] = (_Float16)hreg[nb4][r];
  }
  __syncthreads();
  {
    half8 a[4];
    #pragma unroll
    for (int ks = 0; ks < 4; ks++)
      a[ks] = *(const half8*)&sCat[mt*16 + ml][ks*32 + kg*8];
    #pragma unroll 2
    for (int nb4 = 0; nb4 < 4; nb4++){
      int nbu = nbb + nb4;
      float b1v = xv2_b[nbu*16 + ml];
      float b2v = xv2_b[(nbu+8)*16 + ml];
      float b3v = xv2_b[(nbu+16)*16 + ml];
      f32x4 au1 = {b1v,b1v,b1v,b1v};
      f32x4 au2 = {b2v,b2v,b2v,b2v};
      f32x4 au3 = {b3v,b3v,b3v,b3v};
      #pragma unroll
      for (int ks = 0; ks < 4; ks++){
        au1 = __builtin_amdgcn_mfma_f32_16x16x32_f16(a[ks],
                *(const half8*)(wfxv2 + ((size_t)(nbu*4+ks)*64 + lane)*8), au1, 0,0,0);
        au2 = __builtin_amdgcn_mfma_f32_16x16x32_f16(a[ks],
                *(const half8*)(wfxv2 + ((size_t)((nbu+8)*4+ks)*64 + lane)*8), au2, 0,0,0);
        au3 = __builtin_amdgcn_mfma_f32_16x16x32_f16(a[ks],
                *(const half8*)(wfxv2 + ((size_t)((nbu+16)*4+ks)*64 + lane)*8), au3, 0,0,0);
      }
      #pragma unroll
      for (int r = 0; r < 4; r++){
        int m = mt*16 + kg*4 + r;
        int node = n0 + m;
        if (node >= NN) continue;
        int c = nbu*16 + ml;
        float xu1 = au1[r], xu2 = au2[r], xu3 = au3[r];
        float vdv = vdg[nb4][r];
        size_t px = (size_t)node*128 + c;
        float xn = (xbuf[px] + (float)dx[px]) * INV_SQRT_2f;
        xbuf[px] = xn + (xu1 + xu2*vdv) * INV_SQRT_2f;
        #pragma unroll
        for (int cd = 0; cd < 3; cd++){
          float v1v = v1g[cd][nb4][r];
          size_t pv16 = (size_t)node*768 + 384 + cd*128 + c;
          size_t pdv  = (size_t)node*384 + cd*128 + c;
          float vo = (float)xv16[pv16] + (float)dvec[pdv] + xu3*v1v;
          xv16[pv16] = (_Float16)vo;
        }
      }
    }
  }
}

// ---------------- merged final: energy + gated block 1 + gated block 2 (32 nodes/block) ----------------
__global__ __launch_bounds__(256) void k_final(
    const float* __restrict__ x, const _Float16* __restrict__ xv16,
    const _Float16* __restrict__ wfin,
    const float* __restrict__ be1, const float* __restrict__ we2, const float* __restrict__ be2,
    const float* __restrict__ u1b, const float* __restrict__ u2b,
    const float* __restrict__ g2v2, const float* __restrict__ g2u1b, const float* __restrict__ g2u2,
    const float* __restrict__ g2u2b,
    float* __restrict__ out)
{
  __shared__ _Float16 sCat[32][264];
  __shared__ _Float16 sV2[3][32][72];
  __shared__ _Float16 sH[32][136];
  __shared__ _Float16 sFV[3][32][72];
  __shared__ _Float16 sE1[32][72];
  __shared__ float sR[3][32];
  int t = threadIdx.x;
  int n0 = blockIdx.x * 32;
  int lane = t & 63, w = t >> 6, ml = lane & 15, kg = lane >> 4;
  int mt = w & 1, nh = w >> 1;

  {
    int nd = t >> 3, sb = t & 7;
    int node = n0 + nd;
    if (node < NN){
      const float* xr = x + (size_t)node*128 + sb*16;
      #pragma unroll
      for (int g = 0; g < 4; g++){
        float4 q = *(const float4*)(xr + g*4);
        sCat[nd][sb*16+g*4+0]=(_Float16)q.x; sCat[nd][sb*16+g*4+1]=(_Float16)q.y;
        sCat[nd][sb*16+g*4+2]=(_Float16)q.z; sCat[nd][sb*16+g*4+3]=(_Float16)q.w;
      }
    } else {
      #pragma unroll
      for (int u = 0; u < 16; u++) sCat[nd][sb*16+u] = (_Float16)0.f;
    }
  }
  {
    int arow = n0 + mt*16 + ml;
    bool aok = arow < NN;
    float n1sq[4][4];
    #pragma unroll
    for (int i=0;i<4;i++){
      #pragma unroll
      for (int r=0;r<4;r++) n1sq[i][r]=0.f;
    }
    for (int cd = 0; cd < 3; cd++){
      half8 a[4];
      #pragma unroll
      for (int ks = 0; ks < 4; ks++){
        if (aok){
          a[ks] = *(const half8*)(xv16 + (size_t)arow*768 + 384 + cd*128 + ks*32 + kg*8);
        } else {
          #pragma unroll
          for (int j=0;j<8;j++) a[ks][j] = (_Float16)0.f;
        }
      }
      #pragma unroll
      for (int nb4 = 0; nb4 < 4; nb4++){
        int nb = nh*4 + nb4;
        f32x4 acc = {0.f,0.f,0.f,0.f};
        #pragma unroll
        for (int ks = 0; ks < 4; ks++)
          acc = __builtin_amdgcn_mfma_f32_16x16x32_f16(a[ks],
                  *(const half8*)(wfin + WV1OFF + ((size_t)(nb*4+ks)*64 + lane)*8), acc, 0,0,0);
        #pragma unroll
        for (int r = 0; r < 4; r++) n1sq[nb4][r] += acc[r]*acc[r];
      }
      #pragma unroll
      for (int q = 0; q < 2; q++){
        int nb = nh*2 + q;
        f32x4 acc = {0.f,0.f,0.f,0.f};
        #pragma unroll
        for (int ks = 0; ks < 4; ks++)
          acc = __builtin_amdgcn_mfma_f32_16x16x32_f16(a[ks],
                  *(const half8*)(wfin + WV2OFF + ((size_t)(nb*4+ks)*64 + lane)*8), acc, 0,0,0);
        #pragma unroll
        for (int r = 0; r < 4; r++)
          sV2[cd][mt*16 + kg*4 + r][nb*16 + ml] = (_Float16)acc[r];
      }
    }
    #pragma unroll
    for (int nb4 = 0; nb4 < 4; nb4++){
      #pragma unroll
      for (int r = 0; r < 4; r++)
        sCat[mt*16 + kg*4 + r][128 + nh*64 + nb4*16 + ml] = (_Float16)sqrtf(n1sq[nb4][r]);
    }
  }
  __syncthreads();
  {
    half8 a[8];
    #pragma unroll
    for (int ks = 0; ks < 8; ks++)
      a[ks] = *(const half8*)&sCat[mt*16 + ml][ks*32 + kg*8];
    #pragma unroll
    for (int q = 0; q < 2; q++){
      int nb = nh*2 + q;
      float bias = be1[nb*16 + ml];
      f32x4 acc = {bias, bias, bias, bias};
      #pragma unroll
      for (int ks = 0; ks < 4; ks++)
        acc = __builtin_amdgcn_mfma_f32_16x16x32_f16(a[ks],
                *(const half8*)(wfin + WE1OFF + ((size_t)(nb*4+ks)*64 + lane)*8), acc, 0,0,0);
      #pragma unroll
      for (int r = 0; r < 4; r++)
        sE1[mt*16 + kg*4 + r][nb*16 + ml] = (_Float16)ssilu_f(acc[r]);
    }
    #pragma unroll
    for (int nb4 = 0; nb4 < 4; nb4++){
      int nb = nh*4 + nb4;
      float bias = u1b[nb*16 + ml];
      f32x4 acc = {bias, bias, bias, bias};
      #pragma unroll
      for (int ks = 0; ks < 8; ks++)
        acc = __builtin_amdgcn_mfma_f32_16x16x32_f16(a[ks],
                *(const half8*)(wfin + WU1OFF + ((size_t)(nb*8+ks)*64 + lane)*8), acc, 0,0,0);
      #pragma unroll
      for (int r = 0; r < 4; r++)
        sH[mt*16 + kg*4 + r][nb*16 + ml] = (_Float16)ssilu_f(acc[r]);
    }
  }
  __syncthreads();
  {
    half8 a[4];
    #pragma unroll
    for (int ks = 0; ks < 4; ks++)
      a[ks] = *(const half8*)&sH[mt*16 + ml][ks*32 + kg*8];
    #pragma unroll
    for (int nb4 = 0; nb4 < 4; nb4++){
      int nb = nh*4 + nb4;
      float bias = u2b[nb*16 + ml];
      f32x4 acc = {bias, bias, bias, bias};
      #pragma unroll
      for (int ks = 0; ks < 4; ks++)
        acc = __builtin_amdgcn_mfma_f32_16x16x32_f16(a[ks],
                *(const half8*)(wfin + WU2OFF + ((size_t)(nb*4+ks)*64 + lane)*8), acc, 0,0,0);
      int c = nb*16 + ml;
      #pragma unroll
      for (int r = 0; r < 4; r++){
        int m = mt*16 + kg*4 + r;
        if (c < 64){
          sCat[m][c] = (_Float16)ssilu_f(acc[r]);
        } else {
          float xv = acc[r];
          #pragma unroll
          for (int cd = 0; cd < 3; cd++)
            sFV[cd][m][c-64] = (_Float16)(xv * (float)sV2[cd][m][c-64]);
        }
      }
    }
    float wev = we2[lane];
    #pragma unroll
    for (int i = 0; i < 8; i++){
      int nd = w*8 + i;
      float v = (float)sE1[nd][lane] * wev;
      #pragma unroll
      for (int o2 = 32; o2 > 0; o2 >>= 1) v += __shfl_xor(v, o2, 64);
      int node = n0 + nd;
      if (lane == 0 && node < NN) out[(size_t)node*4 + 0] = v + be2[0];
    }
  }
  __syncthreads();
  {
    float n1sq[2][4];
    #pragma unroll
    for (int q=0;q<2;q++){
      #pragma unroll
      for (int r=0;r<4;r++) n1sq[q][r]=0.f;
    }
    for (int cd = 0; cd < 3; cd++){
      half8 a[2];
      #pragma unroll
      for (int ks = 0; ks < 2; ks++)
        a[ks] = *(const half8*)&sFV[cd][mt*16 + ml][ks*32 + kg*8];
      #pragma unroll
      for (int q = 0; q < 2; q++){
        int nb = nh*2 + q;
        f32x4 acc = {0.f,0.f,0.f,0.f};
        #pragma unroll
        for (int ks = 0; ks < 2; ks++)
          acc = __builtin_amdgcn_mfma_f32_16x16x32_f16(a[ks],
                  *(const half8*)(wfin + G2V1OFF + ((size_t)(nb*2+ks)*64 + lane)*8), acc, 0,0,0);
        #pragma unroll
        for (int r = 0; r < 4; r++) n1sq[q][r] += acc[r]*acc[r];
      }
    }
    #pragma unroll
    for (int q = 0; q < 2; q++){
      #pragma unroll
      for (int r = 0; r < 4; r++)
        sCat[mt*16 + kg*4 + r][64 + (nh*2+q)*16 + ml] = (_Float16)sqrtf(n1sq[q][r]);
    }
    float g2v = g2v2[lane];
    #pragma unroll
    for (int i = 0; i < 8; i++){
      int nd = w*8 + i;
      #pragma unroll
      for (int cd = 0; cd < 3; cd++){
        float v = (float)sFV[cd][nd][lane] * g2v;
        #pragma unroll
        for (int o2 = 32; o2 > 0; o2 >>= 1) v += __shfl_xor(v, o2, 64);
        if (lane == 0) sR[cd][nd] = v;
      }
    }
  }
  __syncthreads();
  {
    half8 a[4];
    #pragma unroll
    for (int ks = 0; ks < 4; ks++)
      a[ks] = *(const half8*)&sCat[mt*16 + ml][ks*32 + kg*8];
    #pragma unroll
    for (int q = 0; q < 2; q++){
      int nb = nh*2 + q;
      float bias = g2u1b[nb*16 + ml];
      f32x4 acc = {bias, bias, bias, bias};
      #pragma unroll
      for (int ks = 0; ks < 4; ks++)
        acc = __builtin_amdgcn_mfma_f32_16x16x32_f16(a[ks],
                *(const half8*)(wfin + G2U1OFF + ((size_t)(nb*4+ks)*64 + lane)*8), acc, 0,0,0);
      #pragma unroll
      for (int r = 0; r < 4; r++)
        sE1[mt*16 + kg*4 + r][nb*16 + ml] = (_Float16)ssilu_f(acc[r]);
    }
  }
  __syncthreads();
  {
    float g2w = g2u2[lane*2 + 1];
    #pragma unroll
    for (int i = 0; i < 8; i++){
      int nd = w*8 + i;
      float v = (float)sE1[nd][lane] * g2w;
      #pragma unroll
      for (int o2 = 32; o2 > 0; o2 >>= 1) v += __shfl_xor(v, o2, 64);
      int node = n0 + nd;
      if (lane == 0 && node < NN){
        float h21 = v + g2u2b[1];
        out[(size_t)node*4 + 1] = h21 * sR[0][nd];
        out[(size_t)node*4 + 2] = h21 * sR[1][nd];
        out[(size_t)node*4 + 3] = h21 * sR[2][nd];
      }
    }
  }
}

extern "C" void kernel_launch(void* const* d_in, const int* in_sizes, int n_in,
                              void* d_out, int out_size, void* d_ws, size_t ws_size,
                              hipStream_t stream)
{
  const float* x_in   = (const float*)d_in[0];
  const float* vec_in = (const float*)d_in[1];
  const int*   eidx   = (const int*)d_in[2];
  const float* erbf   = (const float*)d_in[3];
  const float* evec   = (const float*)d_in[4];
  const float* ln_w  = (const float*)d_in[5];
  const float* ln_b  = (const float*)d_in[6];
  const float* xp1_w = (const float*)d_in[7];
  const float* xp1_b = (const float*)d_in[8];
  const float* xp2_w = (const float*)d_in[9];
  const float* xp2_b = (const float*)d_in[10];
  const float* rbf_w = (const float*)d_in[11];
  const float* rbf_b = (const float*)d_in[12];
  const float* vp_w  = (const float*)d_in[13];
  const float* xv1_w = (const float*)d_in[14];
  const float* xv1_b = (const float*)d_in[15];
  const float* xv2_w = (const float*)d_in[16];
  const float* xv2_b = (const float*)d_in[17];
  const float* we1 = (const float*)d_in[18];
  const float* be1 = (const float*)d_in[19];
  const float* we2 = (const float*)d_in[20];
  const float* be2 = (const float*)d_in[21];
  const float* g1_v1 = (const float*)d_in[22];
  const float* g1_v2 = (const float*)d_in[23];
  const float* g1_u1 = (const float*)d_in[24];
  const float* g1_u1b = (const float*)d_in[25];
  const float* g1_u2 = (const float*)d_in[26];
  const float* g1_u2b = (const float*)d_in[27];
  const float* g2_v1 = (const float*)d_in[28];
  const float* g2_v2 = (const float*)d_in[29];
  const float* g2_u1 = (const float*)d_in[30];
  const float* g2_u1b = (const float*)d_in[31];
  const float* g2_u2 = (const float*)d_in[32];
  const float* g2_u2b = (const float*)d_in[33];
  float* out = (float*)d_out;

  char* base = (char*)d_ws;
  size_t o = 0;
  auto alloc = [&](size_t bytes) -> char* {
    char* p = base + o;
    o = (o + bytes + 255) & ~(size_t)255;
    return p;
  };
  float* x_cur   = (float*)alloc((size_t)NN*128*4);
  _Float16* dx   = (_Float16*)alloc((size_t)NN*128*2);
  _Float16* dvec = (_Float16*)alloc((size_t)NN*384*2);
  _Float16* xv16 = (_Float16*)alloc((size_t)NN*768*2);
  int*   eord    = (int*)alloc((size_t)EE*4);
  int*   off     = (int*)alloc((size_t)(NN+1)*4);
  _Float16* wf   = (_Float16*)alloc((size_t)LL*24576*2);
  float* bsc     = (float*)alloc((size_t)LL*384*4);
  _Float16* wfn  = (_Float16*)alloc((size_t)LL*180224*2);
  _Float16* wfin = (_Float16*)alloc((size_t)WFIN_SZ*2);
  _Float16* eA   = (_Float16*)alloc((size_t)EE*64*2);
  float4* es4    = (float4*)alloc((size_t)EE*16);
  _Float16* rbfh = (_Float16*)alloc((size_t)EE*384*2);
  int* cnt = (int*)dvec;  // pre-layer-0 reuse (dvec region is 7.5 MB; cnt/cur need 80 KB)
  int* cur = cnt + NN;

  hipMemcpyAsync(x_cur, x_in, sizeof(float)*(size_t)NN*128, hipMemcpyDeviceToDevice, stream);

  const int* esrc = eidx;
  const int* edst = eidx + EE;

  hipMemsetAsync(cnt, 0, sizeof(int)*NN, stream);
  k_hist<<<(EE+255)/256, 256, 0, stream>>>(edst, cnt);
  k_scan<<<1, 1024, 0, stream>>>(cnt, off, cur);
  k_fill<<<(EE+255)/256, 256, 0, stream>>>(edst, cur, eord);
  k_sorta<<<(EE*64+255)/256, 256, 0, stream>>>(erbf, eord, eA);
  k_sorte<<<(EE+255)/256, 256, 0, stream>>>(esrc, evec, eord, es4);
  k_packw<<<(LL*24576+255)/256, 256, 0, stream>>>(rbf_w, wf);
  k_packb<<<(LL*384+255)/256, 256, 0, stream>>>(rbf_b, bsc);
  k_cvt16v<<<(NN*384+255)/256, 256, 0, stream>>>(vec_in, xv16);

  {
    PackTab tb;
    for (int l = 0; l < LL; l++){
      _Float16* wb = wfn + (size_t)l*180224;
      tb.s[l*5+0] = xp1_w + (size_t)l*128*128; tb.d[l*5+0] = wb;          tb.K[l*5+0]=128; tb.NO[l*5+0]=128;
      tb.s[l*5+1] = xp2_w + (size_t)l*128*384; tb.d[l*5+1] = wb+16384;    tb.K[l*5+1]=128; tb.NO[l*5+1]=384;
      tb.s[l*5+2] = vp_w  + (size_t)l*128*256; tb.d[l*5+2] = wb+65536;    tb.K[l*5+2]=128; tb.NO[l*5+2]=256;
      tb.s[l*5+3] = xv1_w + (size_t)l*256*128; tb.d[l*5+3] = wb+98304;    tb.K[l*5+3]=256; tb.NO[l*5+3]=128;
      tb.s[l*5+4] = xv2_w + (size_t)l*128*384; tb.d[l*5+4] = wb+131072;   tb.K[l*5+4]=128; tb.NO[l*5+4]=384;
    }
    tb.s[30] = we1;   tb.d[30] = wfin + WE1OFF;  tb.K[30]=128; tb.NO[30]=64;
    tb.s[31] = g1_v1; tb.d[31] = wfin + WV1OFF;  tb.K[31]=128; tb.NO[31]=128;
    tb.s[32] = g1_v2; tb.d[32] = wfin + WV2OFF;  tb.K[32]=128; tb.NO[32]=64;
    tb.s[33] = g1_u1; tb.d[33] = wfin + WU1OFF;  tb.K[33]=256; tb.NO[33]=128;
    tb.s[34] = g1_u2; tb.d[34] = wfin + WU2OFF;  tb.K[34]=128; tb.NO[34]=128;
    tb.s[35] = g2_v1; tb.d[35] = wfin + G2V1OFF; tb.K[35]=64;  tb.NO[35]=64;
    tb.s[36] = g2_u1; tb.d[36] = wfin + G2U1OFF; tb.K[36]=128; tb.NO[36]=64;
    k_packall<<<dim3(24, 37), 256, 0, stream>>>(tb);
  }

  for (int l = 0; l < LL; l++){
    _Float16* wb = wfn + (size_t)l*180224;
    k_xhgemm<<<938, 256, 0, stream>>>(x_cur, ln_w + l*128, ln_b + l*128,
        wb, xp1_b + l*128, wb+16384, xp2_b + l*384, xv16,
        eA, wf + (size_t)l*24576, bsc + (size_t)l*384, rbfh);
    k_edge3<<<NN/4, 256, 0, stream>>>(rbfh, es4, off, xv16, dx, dvec);
    k_node_mfma<<<(NN+31)/32, 256, 0, stream>>>(x_cur, dx, dvec,
        wb+65536, wb+98304, xv1_b + l*128, wb+131072, xv2_b + l*384, xv16);
  }
  k_final<<<(NN+31)/32, 256, 0, stream>>>(x_cur, xv16, wfin,
      be1, we2, be2, g1_u1b, g1_u2b, g2_v2, g2_u1b, g2_u2, g2_u2b, out);
}

// Round 12
// 878.616 us; speedup vs baseline: 1.0857x; 1.0857x over previous
//
#include <hip/hip_runtime.h>
#include <hip/hip_bf16.h>

#define NN 10000
#define EE 160000
#define LL 6

#define INV_SQRT_3f  0.57735026919f
#define INV_SQRT_Hf  0.08838834764832f
#define INV_SQRT_2f  0.70710678118655f

typedef _Float16 half8 __attribute__((ext_vector_type(8)));
typedef float f32x4 __attribute__((ext_vector_type(4)));

#define WE1OFF   0
#define WV1OFF   8192
#define WV2OFF   24576
#define WU1OFF   32768
#define WU2OFF   65536
#define G2V1OFF  81920
#define G2U1OFF  86016
#define WFIN_SZ  94208

__device__ __forceinline__ float ssilu_f(float v){
  float s = 1.0f / (1.0f + __expf(-v));
  return v * s * 1.6666666666667f;
}

// ---------------- CSR build ----------------
__global__ __launch_bounds__(256) void k_hist(const int* __restrict__ edst, int* __restrict__ cnt){
  int i = blockIdx.x*256 + threadIdx.x;
  if (i < EE) atomicAdd(&cnt[edst[i]], 1);
}

__global__ __launch_bounds__(1024) void k_scan(const int* __restrict__ cnt,
                                               int* __restrict__ off, int* __restrict__ cur){
  __shared__ int ps[1024];
  int t = threadIdx.x;
  int base = t*10;
  int local[10];
  int s = 0;
  #pragma unroll
  for (int i=0;i<10;i++){
    int c = (base+i < NN) ? cnt[base+i] : 0;
    local[i] = s; s += c;
  }
  ps[t] = s;
  __syncthreads();
  for (int d=1; d<1024; d<<=1){
    int v = (t>=d) ? ps[t-d] : 0;
    __syncthreads();
    ps[t] += v;
    __syncthreads();
  }
  int pre = (t>0) ? ps[t-1] : 0;
  #pragma unroll
  for (int i=0;i<10;i++){
    int idx = base+i;
    if (idx < NN){ int o = pre + local[i]; off[idx]=o; cur[idx]=o; }
  }
  if (t==1023) off[NN] = ps[1023];
}

__global__ __launch_bounds__(256) void k_fill(const int* __restrict__ edst,
                                              int* __restrict__ cur, int* __restrict__ eord){
  int i = blockIdx.x*256 + threadIdx.x;
  if (i < EE){
    int d = edst[i];
    int p = atomicAdd(&cur[d], 1);
    eord[p] = i;
  }
}

// ---------------- edge pre-sort (once; eord is layer-invariant) ----------------
__global__ __launch_bounds__(256) void k_sorta(const float* __restrict__ erbf,
                                               const int* __restrict__ eord, _Float16* __restrict__ eA){
  long i = (long)blockIdx.x*256 + threadIdx.x;
  if (i >= (long)EE*64) return;
  int j = i & 7, lane = (i >> 3) & 63, kh = (i >> 9) & 1;
  long tile = i >> 10;
  int e = eord[tile*16 + (lane&15)];
  eA[i] = (_Float16)erbf[(size_t)e*64 + kh*32 + (lane>>4)*8 + j];
}

__global__ __launch_bounds__(256) void k_sorte(const int* __restrict__ esrc, const float* __restrict__ evec,
                                               const int* __restrict__ eord, float4* __restrict__ es4){
  int p = blockIdx.x*256 + threadIdx.x;
  if (p >= EE) return;
  int e = eord[p];
  es4[p] = make_float4(evec[(size_t)e*3], evec[(size_t)e*3+1], evec[(size_t)e*3+2],
                       __int_as_float(esrc[e]));
}

// ---------------- pack rbf_w into f16 MFMA B-fragment layout (+ INV_SQRT_3 fold) ----------------
__global__ __launch_bounds__(256) void k_packw(const float* __restrict__ w, _Float16* __restrict__ wf){
  int i = blockIdx.x*256 + threadIdx.x;
  if (i >= LL*24*2*64*8) return;
  int j    = i & 7;
  int lane = (i >> 3) & 63;
  int kh   = (i >> 9) & 1;
  int rest = i >> 10;          // l*24 + nb
  int nb   = rest % 24;
  int l    = rest / 24;
  int k    = 32*kh + 8*(lane>>4) + j;
  int ch   = nb*16 + (lane&15);
  float v = w[((size_t)l*64 + k)*384 + ch];
  if (ch >= 128 && ch < 256) v *= INV_SQRT_3f;
  wf[i] = (_Float16)v;
}

__global__ __launch_bounds__(256) void k_packb(const float* __restrict__ b, float* __restrict__ bsc){
  int i = blockIdx.x*256 + threadIdx.x;
  if (i >= LL*384) return;
  int ch = i % 384;
  float v = b[i];
  if (ch >= 128 && ch < 256) v *= INV_SQRT_3f;
  bsc[i] = v;
}

// ---------------- generic pack: f32 [K][NO] -> f16 B-fragment order ----------------
struct PackTab {
  const float* s[40];
  _Float16* d[40];
  int K[40];
  int NO[40];
};
__global__ __launch_bounds__(256) void k_packall(PackTab tb){
  int e = blockIdx.y;
  int K = tb.K[e], NO = tb.NO[e];
  int tot = K*NO, KS = K >> 5;
  const float* s = tb.s[e];
  _Float16* d = tb.d[e];
  for (int i = blockIdx.x*256 + threadIdx.x; i < tot; i += gridDim.x*256){
    int j = i & 7, lane = (i >> 3) & 63, rest = i >> 9;
    int ks = rest % KS, nb = rest / KS;
    int k = ks*32 + (lane>>4)*8 + j, n = nb*16 + (lane&15);
    d[i] = (_Float16)s[(size_t)k*NO + n];
  }
}

__global__ __launch_bounds__(256) void k_cvt16(const float* __restrict__ v, _Float16* __restrict__ o, int n){
  int i = blockIdx.x*256 + threadIdx.x;
  if (i < n) o[i] = (_Float16)v[i];
}

// ---------------- merged per-layer kernel A: xh MLP (blocks 0..312) + rbfh GEMM (blocks 313..937) ----------------
__global__ __launch_bounds__(256) void k_xhgemm(
    const float* __restrict__ x,
    const float* __restrict__ lnw, const float* __restrict__ lnb,
    const _Float16* __restrict__ wf1, const float* __restrict__ b1,
    const _Float16* __restrict__ wf2, const float* __restrict__ b2,
    _Float16* __restrict__ xh16,
    const _Float16* __restrict__ eA, const _Float16* __restrict__ wf,
    const float* __restrict__ bsc, _Float16* __restrict__ rbfh)
{
  __shared__ _Float16 sA[32][136];
  __shared__ _Float16 sH[32][136];
  int t = threadIdx.x;
  if (blockIdx.x >= 313){
    // ---- rbfh GEMM path: wave = 4 tiles of 16 edges ----
    int ob = (blockIdx.x - 313)*4 + (t >> 6);   // 0..2499
    int lane = t & 63;
    int i0 = ob * 64;
    int tg = ob * 4;
    int ml = lane & 15, kg = lane >> 4;
    half8 a0[4], a1[4];
    #pragma unroll
    for (int tt = 0; tt < 4; tt++){
      a0[tt] = *(const half8*)(eA + ((size_t)((tg+tt)*2+0)*64 + lane)*8);
      a1[tt] = *(const half8*)(eA + ((size_t)((tg+tt)*2+1)*64 + lane)*8);
    }
    #pragma unroll 2
    for (int nb = 0; nb < 24; nb++){
      half8 b0 = *(const half8*)(wf + ((size_t)(nb*2+0)*64 + lane)*8);
      half8 b1h = *(const half8*)(wf + ((size_t)(nb*2+1)*64 + lane)*8);
      float bias = bsc[nb*16 + ml];
      #pragma unroll
      for (int tt = 0; tt < 4; tt++){
        f32x4 acc = {bias, bias, bias, bias};
        acc = __builtin_amdgcn_mfma_f32_16x16x32_f16(a0[tt], b0, acc, 0, 0, 0);
        acc = __builtin_amdgcn_mfma_f32_16x16x32_f16(a1[tt], b1h, acc, 0, 0, 0);
        _Float16* orow = rbfh + (size_t)(i0 + tt*16)*384 + nb*16 + ml;
        #pragma unroll
        for (int r = 0; r < 4; r++)
          orow[(size_t)(kg*4 + r)*384] = (_Float16)acc[r];
      }
    }
    return;
  }
  // ---- xh path ----
  int n0 = blockIdx.x * 32;
  {
    int nd = t >> 3, sb = t & 7;
    int node = n0 + nd;
    float v[16];
    float s = 0.f, ss = 0.f;
    if (node < NN){
      const float* xr = x + (size_t)node*128 + sb*16;
      #pragma unroll
      for (int g = 0; g < 4; g++){
        float4 q = *(const float4*)(xr + g*4);
        v[g*4+0]=q.x; v[g*4+1]=q.y; v[g*4+2]=q.z; v[g*4+3]=q.w;
      }
      #pragma unroll
      for (int u = 0; u < 16; u++){ s += v[u]; ss += v[u]*v[u]; }
    } else {
      #pragma unroll
      for (int u = 0; u < 16; u++) v[u] = 0.f;
    }
    #pragma unroll
    for (int o2 = 4; o2 > 0; o2 >>= 1){
      s  += __shfl_xor(s, o2, 8);
      ss += __shfl_xor(ss, o2, 8);
    }
    float mean = s * (1.0f/128.0f);
    float var  = ss * (1.0f/128.0f) - mean*mean;
    float rstd = rsqrtf(var + 1e-5f);
    #pragma unroll
    for (int u = 0; u < 16; u++){
      int h = sb*16 + u;
      sA[nd][h] = (node < NN) ? (_Float16)((v[u]-mean)*rstd*lnw[h] + lnb[h]) : (_Float16)0.f;
    }
  }
  __syncthreads();
  int lane = t & 63, w = t >> 6, ml = lane & 15, kg = lane >> 4;
  int mt = w >> 1;
  {
    half8 a[4];
    #pragma unroll
    for (int ks = 0; ks < 4; ks++)
      a[ks] = *(const half8*)&sA[mt*16 + ml][ks*32 + kg*8];
    float hout[4][4];
    #pragma unroll
    for (int nb4 = 0; nb4 < 4; nb4++){
      int nb = (w&1)*4 + nb4;
      float bias = b1[nb*16 + ml];
      f32x4 acc = {bias, bias, bias, bias};
      #pragma unroll
      for (int ks = 0; ks < 4; ks++)
        acc = __builtin_amdgcn_mfma_f32_16x16x32_f16(a[ks],
                *(const half8*)(wf1 + ((size_t)(nb*4+ks)*64 + lane)*8), acc, 0,0,0);
      #pragma unroll
      for (int r = 0; r < 4; r++) hout[nb4][r] = ssilu_f(acc[r]);
    }
    #pragma unroll
    for (int nb4 = 0; nb4 < 4; nb4++){
      int nb = (w&1)*4 + nb4;
      #pragma unroll
      for (int r = 0; r < 4; r++)
        sH[mt*16 + kg*4 + r][nb*16 + ml] = (_Float16)hout[nb4][r];
    }
  }
  __syncthreads();
  {
    half8 a[4];
    #pragma unroll
    for (int ks = 0; ks < 4; ks++)
      a[ks] = *(const half8*)&sH[mt*16 + ml][ks*32 + kg*8];
    #pragma unroll 4
    for (int nb12 = 0; nb12 < 12; nb12++){
      int nb = (w&1)*12 + nb12;
      float bias = b2[nb*16 + ml];
      f32x4 acc = {bias, bias, bias, bias};
      #pragma unroll
      for (int ks = 0; ks < 4; ks++)
        acc = __builtin_amdgcn_mfma_f32_16x16x32_f16(a[ks],
                *(const half8*)(wf2 + ((size_t)(nb*4+ks)*64 + lane)*8), acc, 0,0,0);
      #pragma unroll
      for (int r = 0; r < 4; r++){
        int m = mt*16 + kg*4 + r;
        int node = n0 + m;
        if (node < NN) xh16[(size_t)node*384 + nb*16 + ml] = (_Float16)acc[r];
      }
    }
  }
}

// ---------------- edge kernel: one wave per dst node, f16 gathers, f16 outputs ----------------
__global__ __launch_bounds__(256) void k_edge3(
    const _Float16* __restrict__ rbfh,
    const float4* __restrict__ es4, const int* __restrict__ off,
    const _Float16* __restrict__ xh16, const _Float16* __restrict__ vec16,
    _Float16* __restrict__ dx, _Float16* __restrict__ dvec)
{
  int t = threadIdx.x;
  int lane = t & 63;
  int n = blockIdx.x*4 + (t>>6);
  if (n >= NN) return;
  int o0 = off[n], o1 = off[n+1];
  float ax0 = 0.f, ax1 = 0.f;
  float av00=0.f, av01=0.f, av10=0.f, av11=0.f, av20=0.f, av21=0.f;
  #pragma unroll 2
  for (int p = o0; p < o1; p++){
    const _Float16* hr = rbfh + (size_t)p*384;
    float h0 = (float)hr[lane];
    float h1 = (float)hr[64+lane];
    float h2 = (float)hr[128+lane];
    float h3 = (float)hr[192+lane];
    float h4 = (float)hr[256+lane];
    float h5 = (float)hr[320+lane];
    float4 q = es4[p];
    int sN = __float_as_int(q.w);
    const _Float16* xr = xh16 + (size_t)sN*384;
    float m0  = h0 * (float)xr[lane];
    float m1  = h1 * (float)xr[64+lane];
    float m2a = h2 * (float)xr[128+lane];
    float m2b = h3 * (float)xr[192+lane];
    float m3a = h4 * (float)xr[256+lane];
    float m3b = h5 * (float)xr[320+lane];
    ax0 += m0; ax1 += m1;
    const _Float16* vr = vec16 + (size_t)sN*384;
    av00 = fmaf((float)vr[lane],     m2a, av00); av00 = fmaf(m3a, q.x, av00);
    av01 = fmaf((float)vr[64+lane],  m2b, av01); av01 = fmaf(m3b, q.x, av01);
    av10 = fmaf((float)vr[128+lane], m2a, av10); av10 = fmaf(m3a, q.y, av10);
    av11 = fmaf((float)vr[192+lane], m2b, av11); av11 = fmaf(m3b, q.y, av11);
    av20 = fmaf((float)vr[256+lane], m2a, av20); av20 = fmaf(m3a, q.z, av20);
    av21 = fmaf((float)vr[320+lane], m2b, av21); av21 = fmaf(m3b, q.z, av21);
  }
  _Float16* dxr = dx + (size_t)n*128;
  dxr[lane] = (_Float16)ax0; dxr[64+lane] = (_Float16)ax1;
  _Float16* dvr = dvec + (size_t)n*384;
  dvr[lane]     = (_Float16)(av00 * INV_SQRT_Hf);
  dvr[64+lane]  = (_Float16)(av01 * INV_SQRT_Hf);
  dvr[128+lane] = (_Float16)(av10 * INV_SQRT_Hf);
  dvr[192+lane] = (_Float16)(av11 * INV_SQRT_Hf);
  dvr[256+lane] = (_Float16)(av20 * INV_SQRT_Hf);
  dvr[320+lane] = (_Float16)(av21 * INV_SQRT_Hf);
}

// ---------------- node update (MFMA, 32 nodes/block), f16 dx/dvec inputs ----------------
__global__ __launch_bounds__(256) void k_node_mfma(
    float* __restrict__ xbuf, float* __restrict__ vbuf,
    const _Float16* __restrict__ dx, const _Float16* __restrict__ dvec,
    const _Float16* __restrict__ wfvp,
    const _Float16* __restrict__ wfxv1, const float* __restrict__ xv1_b,
    const _Float16* __restrict__ wfxv2, const float* __restrict__ xv2_b,
    _Float16* __restrict__ vec16)
{
  __shared__ _Float16 sV1[96][136];
  __shared__ _Float16 sCat[32][264];
  __shared__ _Float16 sVD[32][128];
  int t = threadIdx.x;
  int n0 = blockIdx.x * 32;
  int lane = t & 63, w = t >> 6, ml = lane & 15, kg = lane >> 4;
  int mt = w & 1, nbb = (w >> 1) * 4;
  float vd[4][4], vn[4][4];
  #pragma unroll
  for (int i=0;i<4;i++){
    #pragma unroll
    for (int r=0;r<4;r++){ vd[i][r]=0.f; vn[i][r]=0.f; }
  }
  int arow = n0 + mt*16 + ml;
  bool aok = arow < NN;
  for (int cd = 0; cd < 3; cd++){
    half8 a[4];
    #pragma unroll
    for (int ks = 0; ks < 4; ks++){
      if (aok){
        const float* vr = vbuf + (size_t)arow*384 + cd*128 + ks*32 + kg*8;
        const _Float16* dr = dvec + (size_t)arow*384 + cd*128 + ks*32 + kg*8;
        float4 q0 = *(const float4*)(vr);
        float4 q1 = *(const float4*)(vr+4);
        half8 dh = *(const half8*)(dr);
        a[ks][0]=(_Float16)(q0.x+(float)dh[0]); a[ks][1]=(_Float16)(q0.y+(float)dh[1]);
        a[ks][2]=(_Float16)(q0.z+(float)dh[2]); a[ks][3]=(_Float16)(q0.w+(float)dh[3]);
        a[ks][4]=(_Float16)(q1.x+(float)dh[4]); a[ks][5]=(_Float16)(q1.y+(float)dh[5]);
        a[ks][6]=(_Float16)(q1.z+(float)dh[6]); a[ks][7]=(_Float16)(q1.w+(float)dh[7]);
      } else {
        #pragma unroll
        for (int j=0;j<8;j++) a[ks][j] = (_Float16)0.f;
      }
    }
    #pragma unroll
    for (int nb4 = 0; nb4 < 4; nb4++){
      int nb1 = nbb + nb4;
      f32x4 acc1 = {0.f,0.f,0.f,0.f}, acc2 = {0.f,0.f,0.f,0.f};
      #pragma unroll
      for (int ks = 0; ks < 4; ks++){
        acc1 = __builtin_amdgcn_mfma_f32_16x16x32_f16(a[ks],
                 *(const half8*)(wfvp + ((size_t)(nb1*4+ks)*64 + lane)*8), acc1, 0,0,0);
        acc2 = __builtin_amdgcn_mfma_f32_16x16x32_f16(a[ks],
                 *(const half8*)(wfvp + ((size_t)((nb1+8)*4+ks)*64 + lane)*8), acc2, 0,0,0);
      }
      #pragma unroll
      for (int r = 0; r < 4; r++){
        float v1v = acc1[r], v2v = acc2[r];
        vd[nb4][r] += v1v*v2v;
        vn[nb4][r] += v2v*v2v;
        sV1[cd*32 + mt*16 + kg*4 + r][nb1*16 + ml] = (_Float16)v1v;
      }
    }
  }
  #pragma unroll
  for (int nb4 = 0; nb4 < 4; nb4++){
    #pragma unroll
    for (int r = 0; r < 4; r++){
      int m = mt*16 + kg*4 + r, c = (nbb+nb4)*16 + ml;
      sVD[m][c] = (_Float16)(vd[nb4][r] * INV_SQRT_Hf);
      sCat[m][128 + c] = (_Float16)sqrtf(vn[nb4][r] + 1e-8f);
    }
  }
  {
    int nd = t >> 3, sb = t & 7;
    int node = n0 + nd;
    if (node < NN){
      const float* xr = xbuf + (size_t)node*128 + sb*16;
      const _Float16* dr = dx + (size_t)node*128 + sb*16;
      half8 da = *(const half8*)(dr);
      half8 db = *(const half8*)(dr+8);
      #pragma unroll
      for (int g = 0; g < 4; g++){
        float4 qa = *(const float4*)(xr + g*4);
        float d0 = (float)((g<2)?da[g*4+0]:db[(g-2)*4+0]);
        float d1 = (float)((g<2)?da[g*4+1]:db[(g-2)*4+1]);
        float d2 = (float)((g<2)?da[g*4+2]:db[(g-2)*4+2]);
        float d3 = (float)((g<2)?da[g*4+3]:db[(g-2)*4+3]);
        sCat[nd][sb*16+g*4+0] = (_Float16)((qa.x+d0)*INV_SQRT_2f);
        sCat[nd][sb*16+g*4+1] = (_Float16)((qa.y+d1)*INV_SQRT_2f);
        sCat[nd][sb*16+g*4+2] = (_Float16)((qa.z+d2)*INV_SQRT_2f);
        sCat[nd][sb*16+g*4+3] = (_Float16)((qa.w+d3)*INV_SQRT_2f);
      }
    } else {
      #pragma unroll
      for (int u = 0; u < 16; u++) sCat[nd][sb*16+u] = (_Float16)0.f;
    }
  }
  __syncthreads();
  float hreg[4][4];
  {
    half8 a[8];
    #pragma unroll
    for (int ks = 0; ks < 8; ks++)
      a[ks] = *(const half8*)&sCat[mt*16 + ml][ks*32 + kg*8];
    #pragma unroll
    for (int nb4 = 0; nb4 < 4; nb4++){
      int nb = (w>>1)*4 + nb4;
      float bias = xv1_b[nb*16 + ml];
      f32x4 acc = {bias, bias, bias, bias};
      #pragma unroll
      for (int ks = 0; ks < 8; ks++)
        acc = __builtin_amdgcn_mfma_f32_16x16x32_f16(a[ks],
                *(const half8*)(wfxv1 + ((size_t)(nb*8+ks)*64 + lane)*8), acc, 0,0,0);
      #pragma unroll
      for (int r = 0; r < 4; r++) hreg[nb4][r] = ssilu_f(acc[r]);
    }
  }
  __syncthreads();
  #pragma unroll
  for (int nb4 = 0; nb4 < 4; nb4++){
    int nb = (w>>1)*4 + nb4;
    #pragma unroll
    for (int r = 0; r < 4; r++)
      sCat[mt*16 + kg*4 + r][nb*16 + ml] = (_Float16)hreg[nb4][r];
  }
  __syncthreads();
  {
    half8 a[4];
    #pragma unroll
    for (int ks = 0; ks < 4; ks++)
      a[ks] = *(const half8*)&sCat[mt*16 + ml][ks*32 + kg*8];
    #pragma unroll 2
    for (int nb4 = 0; nb4 < 4; nb4++){
      int nbu = nbb + nb4;
      float b1v = xv2_b[nbu*16 + ml];
      float b2v = xv2_b[(nbu+8)*16 + ml];
      float b3v = xv2_b[(nbu+16)*16 + ml];
      f32x4 au1 = {b1v,b1v,b1v,b1v};
      f32x4 au2 = {b2v,b2v,b2v,b2v};
      f32x4 au3 = {b3v,b3v,b3v,b3v};
      #pragma unroll
      for (int ks = 0; ks < 4; ks++){
        au1 = __builtin_amdgcn_mfma_f32_16x16x32_f16(a[ks],
                *(const half8*)(wfxv2 + ((size_t)(nbu*4+ks)*64 + lane)*8), au1, 0,0,0);
        au2 = __builtin_amdgcn_mfma_f32_16x16x32_f16(a[ks],
                *(const half8*)(wfxv2 + ((size_t)((nbu+8)*4+ks)*64 + lane)*8), au2, 0,0,0);
        au3 = __builtin_amdgcn_mfma_f32_16x16x32_f16(a[ks],
                *(const half8*)(wfxv2 + ((size_t)((nbu+16)*4+ks)*64 + lane)*8), au3, 0,0,0);
      }
      #pragma unroll
      for (int r = 0; r < 4; r++){
        int m = mt*16 + kg*4 + r;
        int node = n0 + m;
        if (node >= NN) continue;
        int c = nbu*16 + ml;
        float xu1 = au1[r], xu2 = au2[r], xu3 = au3[r];
        float vdv = (float)sVD[m][c];
        size_t px = (size_t)node*128 + c;
        float xn = (xbuf[px] + (float)dx[px]) * INV_SQRT_2f;
        xbuf[px] = xn + (xu1 + xu2*vdv) * INV_SQRT_2f;
        #pragma unroll
        for (int cd = 0; cd < 3; cd++){
          float v1v = (float)sV1[cd*32 + m][c];
          size_t pv = (size_t)node*384 + cd*128 + c;
          float vo = vbuf[pv] + (float)dvec[pv] + xu3*v1v;
          vbuf[pv] = vo;
          vec16[pv] = (_Float16)vo;
        }
      }
    }
  }
}

// ---------------- merged final: energy + gated block 1 + gated block 2 (32 nodes/block) ----------------
__global__ __launch_bounds__(256) void k_final(
    const float* __restrict__ x, const float* __restrict__ vec,
    const _Float16* __restrict__ wfin,
    const float* __restrict__ be1, const float* __restrict__ we2, const float* __restrict__ be2,
    const float* __restrict__ u1b, const float* __restrict__ u2b,
    const float* __restrict__ g2v2, const float* __restrict__ g2u1b, const float* __restrict__ g2u2,
    const float* __restrict__ g2u2b,
    float* __restrict__ out)
{
  __shared__ _Float16 sCat[32][264];
  __shared__ _Float16 sV2[3][32][72];
  __shared__ _Float16 sH[32][136];
  __shared__ _Float16 sFV[3][32][72];
  __shared__ _Float16 sE1[32][72];
  __shared__ float sR[3][32];
  int t = threadIdx.x;
  int n0 = blockIdx.x * 32;
  int lane = t & 63, w = t >> 6, ml = lane & 15, kg = lane >> 4;
  int mt = w & 1, nh = w >> 1;

  {
    int nd = t >> 3, sb = t & 7;
    int node = n0 + nd;
    if (node < NN){
      const float* xr = x + (size_t)node*128 + sb*16;
      #pragma unroll
      for (int g = 0; g < 4; g++){
        float4 q = *(const float4*)(xr + g*4);
        sCat[nd][sb*16+g*4+0]=(_Float16)q.x; sCat[nd][sb*16+g*4+1]=(_Float16)q.y;
        sCat[nd][sb*16+g*4+2]=(_Float16)q.z; sCat[nd][sb*16+g*4+3]=(_Float16)q.w;
      }
    } else {
      #pragma unroll
      for (int u = 0; u < 16; u++) sCat[nd][sb*16+u] = (_Float16)0.f;
    }
  }
  {
    int arow = n0 + mt*16 + ml;
    bool aok = arow < NN;
    float n1sq[4][4];
    #pragma unroll
    for (int i=0;i<4;i++){
      #pragma unroll
      for (int r=0;r<4;r++) n1sq[i][r]=0.f;
    }
    for (int cd = 0; cd < 3; cd++){
      half8 a[4];
      #pragma unroll
      for (int ks = 0; ks < 4; ks++){
        if (aok){
          const float* vr = vec + (size_t)arow*384 + cd*128 + ks*32 + kg*8;
          float4 q0 = *(const float4*)(vr);
          float4 q1 = *(const float4*)(vr+4);
          a[ks][0]=(_Float16)q0.x; a[ks][1]=(_Float16)q0.y; a[ks][2]=(_Float16)q0.z; a[ks][3]=(_Float16)q0.w;
          a[ks][4]=(_Float16)q1.x; a[ks][5]=(_Float16)q1.y; a[ks][6]=(_Float16)q1.z; a[ks][7]=(_Float16)q1.w;
        } else {
          #pragma unroll
          for (int j=0;j<8;j++) a[ks][j] = (_Float16)0.f;
        }
      }
      #pragma unroll
      for (int nb4 = 0; nb4 < 4; nb4++){
        int nb = nh*4 + nb4;
        f32x4 acc = {0.f,0.f,0.f,0.f};
        #pragma unroll
        for (int ks = 0; ks < 4; ks++)
          acc = __builtin_amdgcn_mfma_f32_16x16x32_f16(a[ks],
                  *(const half8*)(wfin + WV1OFF + ((size_t)(nb*4+ks)*64 + lane)*8), acc, 0,0,0);
        #pragma unroll
        for (int r = 0; r < 4; r++) n1sq[nb4][r] += acc[r]*acc[r];
      }
      #pragma unroll
      for (int q = 0; q < 2; q++){
        int nb = nh*2 + q;
        f32x4 acc = {0.f,0.f,0.f,0.f};
        #pragma unroll
        for (int ks = 0; ks < 4; ks++)
          acc = __builtin_amdgcn_mfma_f32_16x16x32_f16(a[ks],
                  *(const half8*)(wfin + WV2OFF + ((size_t)(nb*4+ks)*64 + lane)*8), acc, 0,0,0);
        #pragma unroll
        for (int r = 0; r < 4; r++)
          sV2[cd][mt*16 + kg*4 + r][nb*16 + ml] = (_Float16)acc[r];
      }
    }
    #pragma unroll
    for (int nb4 = 0; nb4 < 4; nb4++){
      #pragma unroll
      for (int r = 0; r < 4; r++)
        sCat[mt*16 + kg*4 + r][128 + nh*64 + nb4*16 + ml] = (_Float16)sqrtf(n1sq[nb4][r]);
    }
  }
  __syncthreads();
  {
    half8 a[8];
    #pragma unroll
    for (int ks = 0; ks < 8; ks++)
      a[ks] = *(const half8*)&sCat[mt*16 + ml][ks*32 + kg*8];
    #pragma unroll
    for (int q = 0; q < 2; q++){
      int nb = nh*2 + q;
      float bias = be1[nb*16 + ml];
      f32x4 acc = {bias, bias, bias, bias};
      #pragma unroll
      for (int ks = 0; ks < 4; ks++)
        acc = __builtin_amdgcn_mfma_f32_16x16x32_f16(a[ks],
                *(const half8*)(wfin + WE1OFF + ((size_t)(nb*4+ks)*64 + lane)*8), acc, 0,0,0);
      #pragma unroll
      for (int r = 0; r < 4; r++)
        sE1[mt*16 + kg*4 + r][nb*16 + ml] = (_Float16)ssilu_f(acc[r]);
    }
    #pragma unroll
    for (int nb4 = 0; nb4 < 4; nb4++){
      int nb = nh*4 + nb4;
      float bias = u1b[nb*16 + ml];
      f32x4 acc = {bias, bias, bias, bias};
      #pragma unroll
      for (int ks = 0; ks < 8; ks++)
        acc = __builtin_amdgcn_mfma_f32_16x16x32_f16(a[ks],
                *(const half8*)(wfin + WU1OFF + ((size_t)(nb*8+ks)*64 + lane)*8), acc, 0,0,0);
      #pragma unroll
      for (int r = 0; r < 4; r++)
        sH[mt*16 + kg*4 + r][nb*16 + ml] = (_Float16)ssilu_f(acc[r]);
    }
  }
  __syncthreads();
  {
    half8 a[4];
    #pragma unroll
    for (int ks = 0; ks < 4; ks++)
      a[ks] = *(const half8*)&sH[mt*16 + ml][ks*32 + kg*8];
    #pragma unroll
    for (int nb4 = 0; nb4 < 4; nb4++){
      int nb = nh*4 + nb4;
      float bias = u2b[nb*16 + ml];
      f32x4 acc = {bias, bias, bias, bias};
      #pragma unroll
      for (int ks = 0; ks < 4; ks++)
        acc = __builtin_amdgcn_mfma_f32_16x16x32_f16(a[ks],
                *(const half8*)(wfin + WU2OFF + ((size_t)(nb*4+ks)*64 + lane)*8), acc, 0,0,0);
      int c = nb*16 + ml;
      #pragma unroll
      for (int r = 0; r < 4; r++){
        int m = mt*16 + kg*4 + r;
        if (c < 64){
          sCat[m][c] = (_Float16)ssilu_f(acc[r]);
        } else {
          float xv = acc[r];
          #pragma unroll
          for (int cd = 0; cd < 3; cd++)
            sFV[cd][m][c-64] = (_Float16)(xv * (float)sV2[cd][m][c-64]);
        }
      }
    }
    float wev = we2[lane];
    #pragma unroll
    for (int i = 0; i < 8; i++){
      int nd = w*8 + i;
      float v = (float)sE1[nd][lane] * wev;
      #pragma unroll
      for (int o2 = 32; o2 > 0; o2 >>= 1) v += __shfl_xor(v, o2, 64);
      int node = n0 + nd;
      if (lane == 0 && node < NN) out[(size_t)node*4 + 0] = v + be2[0];
    }
  }
  __syncthreads();
  {
    float n1sq[2][4];
    #pragma unroll
    for (int q=0;q<2;q++){
      #pragma unroll
      for (int r=0;r<4;r++) n1sq[q][r]=0.f;
    }
    for (int cd = 0; cd < 3; cd++){
      half8 a[2];
      #pragma unroll
      for (int ks = 0; ks < 2; ks++)
        a[ks] = *(const half8*)&sFV[cd][mt*16 + ml][ks*32 + kg*8];
      #pragma unroll
      for (int q = 0; q < 2; q++){
        int nb = nh*2 + q;
        f32x4 acc = {0.f,0.f,0.f,0.f};
        #pragma unroll
        for (int ks = 0; ks < 2; ks++)
          acc = __builtin_amdgcn_mfma_f32_16x16x32_f16(a[ks],
                  *(const half8*)(wfin + G2V1OFF + ((size_t)(nb*2+ks)*64 + lane)*8), acc, 0,0,0);
        #pragma unroll
        for (int r = 0; r < 4; r++) n1sq[q][r] += acc[r]*acc[r];
      }
    }
    #pragma unroll
    for (int q = 0; q < 2; q++){
      #pragma unroll
      for (int r = 0; r < 4; r++)
        sCat[mt*16 + kg*4 + r][64 + (nh*2+q)*16 + ml] = (_Float16)sqrtf(n1sq[q][r]);
    }
    float g2v = g2v2[lane];
    #pragma unroll
    for (int i = 0; i < 8; i++){
      int nd = w*8 + i;
      #pragma unroll
      for (int cd = 0; cd < 3; cd++){
        float v = (float)sFV[cd][nd][lane] * g2v;
        #pragma unroll
        for (int o2 = 32; o2 > 0; o2 >>= 1) v += __shfl_xor(v, o2, 64);
        if (lane == 0) sR[cd][nd] = v;
      }
    }
  }
  __syncthreads();
  {
    half8 a[4];
    #pragma unroll
    for (int ks = 0; ks < 4; ks++)
      a[ks] = *(const half8*)&sCat[mt*16 + ml][ks*32 + kg*8];
    #pragma unroll
    for (int q = 0; q < 2; q++){
      int nb = nh*2 + q;
      float bias = g2u1b[nb*16 + ml];
      f32x4 acc = {bias, bias, bias, bias};
      #pragma unroll
      for (int ks = 0; ks < 4; ks++)
        acc = __builtin_amdgcn_mfma_f32_16x16x32_f16(a[ks],
                *(const half8*)(wfin + G2U1OFF + ((size_t)(nb*4+ks)*64 + lane)*8), acc, 0,0,0);
      #pragma unroll
      for (int r = 0; r < 4; r++)
        sE1[mt*16 + kg*4 + r][nb*16 + ml] = (_Float16)ssilu_f(acc[r]);
    }
  }
  __syncthreads();
  {
    float g2w = g2u2[lane*2 + 1];
    #pragma unroll
    for (int i = 0; i < 8; i++){
      int nd = w*8 + i;
      float v = (float)sE1[nd][lane] * g2w;
      #pragma unroll
      for (int o2 = 32; o2 > 0; o2 >>= 1) v += __shfl_xor(v, o2, 64);
      int node = n0 + nd;
      if (lane == 0 && node < NN){
        float h21 = v + g2u2b[1];
        out[(size_t)node*4 + 1] = h21 * sR[0][nd];
        out[(size_t)node*4 + 2] = h21 * sR[1][nd];
        out[(size_t)node*4 + 3] = h21 * sR[2][nd];
      }
    }
  }
}

extern "C" void kernel_launch(void* const* d_in, const int* in_sizes, int n_in,
                              void* d_out, int out_size, void* d_ws, size_t ws_size,
                              hipStream_t stream)
{
  const float* x_in   = (const float*)d_in[0];
  const float* vec_in = (const float*)d_in[1];
  const int*   eidx   = (const int*)d_in[2];
  const float* erbf   = (const float*)d_in[3];
  const float* evec   = (const float*)d_in[4];
  const float* ln_w  = (const float*)d_in[5];
  const float* ln_b  = (const float*)d_in[6];
  const float* xp1_w = (const float*)d_in[7];
  const float* xp1_b = (const float*)d_in[8];
  const float* xp2_w = (const float*)d_in[9];
  const float* xp2_b = (const float*)d_in[10];
  const float* rbf_w = (const float*)d_in[11];
  const float* rbf_b = (const float*)d_in[12];
  const float* vp_w  = (const float*)d_in[13];
  const float* xv1_w = (const float*)d_in[14];
  const float* xv1_b = (const float*)d_in[15];
  const float* xv2_w = (const float*)d_in[16];
  const float* xv2_b = (const float*)d_in[17];
  const float* we1 = (const float*)d_in[18];
  const float* be1 = (const float*)d_in[19];
  const float* we2 = (const float*)d_in[20];
  const float* be2 = (const float*)d_in[21];
  const float* g1_v1 = (const float*)d_in[22];
  const float* g1_v2 = (const float*)d_in[23];
  const float* g1_u1 = (const float*)d_in[24];
  const float* g1_u1b = (const float*)d_in[25];
  const float* g1_u2 = (const float*)d_in[26];
  const float* g1_u2b = (const float*)d_in[27];
  const float* g2_v1 = (const float*)d_in[28];
  const float* g2_v2 = (const float*)d_in[29];
  const float* g2_u1 = (const float*)d_in[30];
  const float* g2_u1b = (const float*)d_in[31];
  const float* g2_u2 = (const float*)d_in[32];
  const float* g2_u2b = (const float*)d_in[33];
  float* out = (float*)d_out;

  char* base = (char*)d_ws;
  size_t o = 0;
  auto alloc = [&](size_t bytes) -> char* {
    char* p = base + o;
    o = (o + bytes + 255) & ~(size_t)255;
    return p;
  };
  float* x_cur   = (float*)alloc((size_t)NN*128*4);
  float* vec_cur = (float*)alloc((size_t)NN*384*4);
  _Float16* dx   = (_Float16*)alloc((size_t)NN*128*2);
  _Float16* dvec = (_Float16*)alloc((size_t)NN*384*2);
  _Float16* xh16 = (_Float16*)alloc((size_t)NN*384*2);
  _Float16* vec16= (_Float16*)alloc((size_t)NN*384*2);
  int*   eord    = (int*)alloc((size_t)EE*4);
  int*   off     = (int*)alloc((size_t)(NN+1)*4);
  _Float16* wf   = (_Float16*)alloc((size_t)LL*24576*2);
  float* bsc     = (float*)alloc((size_t)LL*384*4);
  _Float16* wfn  = (_Float16*)alloc((size_t)LL*180224*2);
  _Float16* wfin = (_Float16*)alloc((size_t)WFIN_SZ*2);
  _Float16* eA   = (_Float16*)alloc((size_t)EE*64*2);
  float4* es4    = (float4*)alloc((size_t)EE*16);
  _Float16* rbfh = (_Float16*)alloc((size_t)EE*384*2);
  int* cnt = (int*)dx;  // pre-layer-0 reuse (dx region is 2.5 MB; cnt/cur need 80 KB)
  int* cur = cnt + NN;

  hipMemcpyAsync(x_cur, x_in, sizeof(float)*(size_t)NN*128, hipMemcpyDeviceToDevice, stream);
  hipMemcpyAsync(vec_cur, vec_in, sizeof(float)*(size_t)NN*384, hipMemcpyDeviceToDevice, stream);

  const int* esrc = eidx;
  const int* edst = eidx + EE;

  hipMemsetAsync(cnt, 0, sizeof(int)*NN, stream);
  k_hist<<<(EE+255)/256, 256, 0, stream>>>(edst, cnt);
  k_scan<<<1, 1024, 0, stream>>>(cnt, off, cur);
  k_fill<<<(EE+255)/256, 256, 0, stream>>>(edst, cur, eord);
  k_sorta<<<(EE*64+255)/256, 256, 0, stream>>>(erbf, eord, eA);
  k_sorte<<<(EE+255)/256, 256, 0, stream>>>(esrc, evec, eord, es4);
  k_packw<<<(LL*24576+255)/256, 256, 0, stream>>>(rbf_w, wf);
  k_packb<<<(LL*384+255)/256, 256, 0, stream>>>(rbf_b, bsc);
  k_cvt16<<<(NN*384+255)/256, 256, 0, stream>>>(vec_in, vec16, NN*384);

  {
    PackTab tb;
    for (int l = 0; l < LL; l++){
      _Float16* wb = wfn + (size_t)l*180224;
      tb.s[l*5+0] = xp1_w + (size_t)l*128*128; tb.d[l*5+0] = wb;          tb.K[l*5+0]=128; tb.NO[l*5+0]=128;
      tb.s[l*5+1] = xp2_w + (size_t)l*128*384; tb.d[l*5+1] = wb+16384;    tb.K[l*5+1]=128; tb.NO[l*5+1]=384;
      tb.s[l*5+2] = vp_w  + (size_t)l*128*256; tb.d[l*5+2] = wb+65536;    tb.K[l*5+2]=128; tb.NO[l*5+2]=256;
      tb.s[l*5+3] = xv1_w + (size_t)l*256*128; tb.d[l*5+3] = wb+98304;    tb.K[l*5+3]=256; tb.NO[l*5+3]=128;
      tb.s[l*5+4] = xv2_w + (size_t)l*128*384; tb.d[l*5+4] = wb+131072;   tb.K[l*5+4]=128; tb.NO[l*5+4]=384;
    }
    tb.s[30] = we1;   tb.d[30] = wfin + WE1OFF;  tb.K[30]=128; tb.NO[30]=64;
    tb.s[31] = g1_v1; tb.d[31] = wfin + WV1OFF;  tb.K[31]=128; tb.NO[31]=128;
    tb.s[32] = g1_v2; tb.d[32] = wfin + WV2OFF;  tb.K[32]=128; tb.NO[32]=64;
    tb.s[33] = g1_u1; tb.d[33] = wfin + WU1OFF;  tb.K[33]=256; tb.NO[33]=128;
    tb.s[34] = g1_u2; tb.d[34] = wfin + WU2OFF;  tb.K[34]=128; tb.NO[34]=128;
    tb.s[35] = g2_v1; tb.d[35] = wfin + G2V1OFF; tb.K[35]=64;  tb.NO[35]=64;
    tb.s[36] = g2_u1; tb.d[36] = wfin + G2U1OFF; tb.K[36]=128; tb.NO[36]=64;
    k_packall<<<dim3(24, 37), 256, 0, stream>>>(tb);
  }

  for (int l = 0; l < LL; l++){
    _Float16* wb = wfn + (size_t)l*180224;
    k_xhgemm<<<938, 256, 0, stream>>>(x_cur, ln_w + l*128, ln_b + l*128,
        wb, xp1_b + l*128, wb+16384, xp2_b + l*384, xh16,
        eA, wf + (size_t)l*24576, bsc + (size_t)l*384, rbfh);
    k_edge3<<<NN/4, 256, 0, stream>>>(rbfh, es4, off, xh16, vec16, dx, dvec);
    k_node_mfma<<<(NN+31)/32, 256, 0, stream>>>(x_cur, vec_cur, dx, dvec,
        wb+65536, wb+98304, xv1_b + l*128, wb+131072, xv2_b + l*384, vec16);
  }
  k_final<<<(NN+31)/32, 256, 0, stream>>>(x_cur, vec_cur, wfin,
      be1, we2, be2, g1_u1b, g1_u2b, g2_v2, g2_u1b, g2_u2, g2_u2b, out);
}